// Round 1
// baseline (253.741 us; speedup 1.0000x reference)
//
#include <hip/hip_runtime.h>
#include <math.h>

// ---- geometry ----
// Grid 50^3, coords shifted +1 -> occupy [1,50]. Dense key = (z*GY+y)*64+x.
// 8-deep z bricks probe z up to 57 -> z-dim 58.
#define GY 54
#define ZD 58
#define NROWS (ZD*GY*64)      // 200448 keys

// brick 8x4x8 = 256 output voxels per block; halo 10x6x10 = 600 rows
#define HX 10
#define HY 6
#define HXY 60                // halo rows per z-slice
#define NH 600
#define NBX 7
#define NBY 13
#define NBZ 7
#define NBRICK (NBX*NBY*NBZ)  // 637
#define SLAB 80               // ceil(637/8)

// B staged in two tap chunks so LDS fits 3 blocks/CU
#define TAPS_C0 14
#define TAPS_C1 13

typedef __bf16  bf16x8 __attribute__((ext_vector_type(8)));
typedef float  f32x16 __attribute__((ext_vector_type(16)));

// ---- fused prep: maps + reverse keys + W -> Wt4 ----
// Wt4 layout now carries the bank-conflict swizzle: granule for (p,t,co,h)
// sits at ((p*27+t)*128 + co*2 + (h ^ ((co>>2)&1))); h = cin-half within quarter.
// 8 consecutive cout rows then cover all 8 bank quads instead of 4.
__global__ void prep_kernel(const float* __restrict__ ipos, int n,
                            const float* __restrict__ opos, int m,
                            const float* __restrict__ vsp,
                            const float* __restrict__ W,
                            int* __restrict__ imap, int* __restrict__ ikey,
                            int* __restrict__ omap, int* __restrict__ okey,
                            __bf16* __restrict__ Wt4) {
    int i = blockIdx.x * 256 + threadIdx.x;
    float vs = vsp[0];
    if (i < n) {
        int x = (int)floorf(ipos[3*i+0] / vs) + 1;
        int y = (int)floorf(ipos[3*i+1] / vs) + 1;
        int z = (int)floorf(ipos[3*i+2] / vs) + 1;
        int key = (z * GY + y) * 64 + x;
        ikey[i] = key;
        imap[key] = i;
    } else if (i < n + m) {
        int j = i - n;
        int x = (int)floorf(opos[3*j+0] / vs) + 1;
        int y = (int)floorf(opos[3*j+1] / vs) + 1;
        int z = (int)floorf(opos[3*j+2] / vs) + 1;
        int key = (z * GY + y) * 64 + x;
        okey[j] = key;
        omap[key] = j;
    } else if (i < n + m + 27*64*64) {
        int k  = i - n - m;
        int t  = k >> 12;
        int r  = k & 4095;
        int ci = r >> 6;
        int co = r & 63;
        int p   = ci >> 4;
        int cil = ci & 15;
        int h   = cil >> 3;
        int j   = cil & 7;
        int g   = ((p * 27 + t) << 7) + (co << 1) + (h ^ ((co >> 2) & 1));
        Wt4[(g << 3) + j] = (__bf16)W[k];
    }
}

__global__ __launch_bounds__(256, 3) void conv_kernel(
    const float* __restrict__ feats,    // [N,64] fp32
    const __bf16* __restrict__ Wt4,     // [4][27][64co x 16ci] (swizzled granules)
    const float* __restrict__ bias,     // [64]
    const int*   __restrict__ imap,
    const int*   __restrict__ ikey,
    const int*   __restrict__ omap,
    const int*   __restrict__ okey,
    float*       __restrict__ out,      // [M,64]
    int N, int M)
{
    __shared__ __align__(16) __bf16 halo[NH * 16];            // 19200 B (row = 16 cin, 32B, halves swizzled)
    __shared__ __align__(16) __bf16 Bq[TAPS_C0 * 64 * 16];    // 28672 B (one tap chunk, quarter-K)
    __shared__ int ridx[NH];                                  //  2400 B
    __shared__ int obuf[256];                                 //  1024 B
    // total ~51.3 KB -> 3 blocks/CU (12 waves/CU); all 637 bricks co-resident

    const int tid = threadIdx.x;

    // XCD slab swizzle
    int q = (blockIdx.x & 7) * SLAB + (blockIdx.x >> 3);
    if (q >= NBRICK) return;   // block-uniform exit before any barrier
    const int bx = q % NBX;
    int rem = q / NBX;
    const int by = rem % NBY;
    const int bz = rem / NBY;

    // ---- resolve halo row indices (validated) + output rows ----
    #pragma unroll
    for (int it = 0; it < 3; ++it) {
        int r = it * 256 + tid;
        if (r < NH) {
            int xs = r % HX;
            int t2 = r / HX;
            int ys = t2 % HY;
            int zs = t2 / HY;
            int key = ((bz*8 + zs) * GY + (by*4 + ys)) * 64 + (bx*8 + xs);
            int idx = imap[key];
            int c = min(max(idx, 0), N - 1);
            ridx[r] = (idx >= 0 && idx < N && ikey[c] == key) ? idx : -1;
        }
    }
    {
        int x = tid & 7, y = (tid >> 3) & 3, z = tid >> 5;
        int key = ((bz*8 + z + 1) * GY + (by*4 + y + 1)) * 64 + (bx*8 + x + 1);
        int o = omap[key];
        int c = min(max(o, 0), M - 1);
        obuf[tid] = (o >= 0 && o < M && okey[c] == key) ? o : -1;
    }

    // compute roles: wave owns z-slices {2w, 2w+1} (2 m-tiles) x both n-tiles
    const int wave  = tid >> 6;
    const int lane  = tid & 63;
    const int lrow  = lane & 31;
    const int halfk = lane >> 5;
    const int xv = lrow & 7, yv = (lrow >> 3) & 3;
    // A row index (halo row units) for m-tile 0 of this wave, before tap offset
    const int arow0 = (2*wave + 1) * HXY + (yv + 1) * HX + (xv + 1);
    // B read pointers: swizzle is baked into Wt4, lane constants -> computed once.
    // granule(co,h) = co*2 + (h ^ ((co>>2)&1)); co+32 flips only bit3 of co>>2,
    // so n-tile 1 keeps the same XOR: Bb1 = Bb0 + 512 elements.
    const __bf16* Bb0 = Bq + (((lrow << 1) + (halfk ^ ((lrow >> 2) & 1))) << 3);
    const __bf16* Bb1 = Bb0 + 512;

    f32x16 acc00, acc01, acc10, acc11;
    #pragma unroll
    for (int i = 0; i < 16; ++i) { acc00[i]=0.f; acc01[i]=0.f; acc10[i]=0.f; acc11[i]=0.f; }

    // one tap of work: reads swizzled halo halves; HXY=60 is 4*odd so the
    // z+1 m-tile's swizzle bit is the complement of m-tile 0's.
    auto tap_body = [&](int t, int tc) {
        const int dx = t % 3 - 1;
        const int dy = (t / 3) % 3 - 1;
        const int dz = t / 9 - 1;
        const int drow = dz * HXY + dy * HX + dx;
        int ar0 = arow0 + drow;
        int sw0 = halfk ^ ((ar0 >> 2) & 1);
        bf16x8 a0 = *(const bf16x8*)(halo + ar0 * 16 + (sw0 << 3));
        bf16x8 a1 = *(const bf16x8*)(halo + (ar0 + HXY) * 16 + ((sw0 ^ 1) << 3));
        bf16x8 b0 = *(const bf16x8*)(Bb0 + tc * 1024);
        bf16x8 b1 = *(const bf16x8*)(Bb1 + tc * 1024);
        acc00 = __builtin_amdgcn_mfma_f32_32x32x16_bf16(a0, b0, acc00, 0, 0, 0);
        acc01 = __builtin_amdgcn_mfma_f32_32x32x16_bf16(a0, b1, acc01, 0, 0, 0);
        acc10 = __builtin_amdgcn_mfma_f32_32x32x16_bf16(a1, b0, acc10, 0, 0, 0);
        acc11 = __builtin_amdgcn_mfma_f32_32x32x16_bf16(a1, b1, acc11, 0, 0, 0);
    };

    __syncthreads();   // ridx + obuf visible

    #pragma unroll 1
    for (int p = 0; p < 4; ++p) {
        if (p) __syncthreads();   // previous pass's readers done before overwrite

        // ---- fill halo quarter: 600 rows x 16 cin (fp32 -> bf16), swizzled halves ----
        #pragma unroll
        for (int it = 0; it < 5; ++it) {
            int task = it * 256 + tid;
            if (task < NH * 2) {
                int r = task >> 1, hf = task & 1;   // hf: 8-channel half of the quarter
                int idx = ridx[r];
                bf16x8 v;
                if (idx >= 0) {
                    const float4* s = (const float4*)(feats + (size_t)idx * 64 + p * 16 + hf * 8);
                    float4 f0 = s[0], f1 = s[1];
                    v[0]=(__bf16)f0.x; v[1]=(__bf16)f0.y; v[2]=(__bf16)f0.z; v[3]=(__bf16)f0.w;
                    v[4]=(__bf16)f1.x; v[5]=(__bf16)f1.y; v[6]=(__bf16)f1.z; v[7]=(__bf16)f1.w;
                } else {
                    #pragma unroll
                    for (int j = 0; j < 8; ++j) v[j] = (__bf16)0.f;
                }
                int sw = hf ^ ((r >> 2) & 1);
                *(bf16x8*)(halo + r * 16 + (sw << 3)) = v;
            }
        }

        // ---- fill B chunk 0: taps 0..13 (linear copy, Wt4 pre-swizzled) ----
        {
            const __bf16* Wp = Wt4 + (size_t)p * 27648;
            #pragma unroll
            for (int it = 0; it < 7; ++it) {
                int task = it * 256 + tid;           // 1792 chunks exactly
                *(bf16x8*)(Bq + task * 8) = *(const bf16x8*)(Wp + task * 8);
            }
        }

        __syncthreads();   // halo + Bq chunk 0 visible

        #pragma unroll
        for (int t = 0; t < TAPS_C0; ++t) tap_body(t, t);

        __syncthreads();   // chunk-0 readers done before Bq overwrite

        // ---- fill B chunk 1: taps 14..26 ----
        {
            const __bf16* Wp = Wt4 + (size_t)p * 27648 + TAPS_C0 * 1024;
            #pragma unroll
            for (int it = 0; it < 7; ++it) {
                int task = it * 256 + tid;           // 1664 chunks
                if (task < TAPS_C1 * 128)
                    *(bf16x8*)(Bq + task * 8) = *(const bf16x8*)(Wp + task * 8);
            }
        }

        __syncthreads();   // Bq chunk 1 visible (halo untouched)

        #pragma unroll
        for (int t = TAPS_C0; t < 27; ++t) tap_body(t, t - TAPS_C0);
    }

    // ---- epilogue: C/D layout col=lane&31, row=(reg&3)+8*(reg>>2)+4*(lane>>5) ----
    const int col0 = lrow, col1 = 32 + lrow;
    const float bv0 = bias[col0], bv1 = bias[col1];
    #pragma unroll
    for (int r = 0; r < 16; ++r) {
        int mrow = (r & 3) + 8 * (r >> 2) + 4 * halfk;
        int o0 = obuf[(2*wave)     * 32 + mrow];
        int o1 = obuf[(2*wave + 1) * 32 + mrow];
        if (o0 >= 0) {
            out[(size_t)o0 * 64 + col0] = acc00[r] + bv0;
            out[(size_t)o0 * 64 + col1] = acc01[r] + bv1;
        }
        if (o1 >= 0) {
            out[(size_t)o1 * 64 + col0] = acc10[r] + bv0;
            out[(size_t)o1 * 64 + col1] = acc11[r] + bv1;
        }
    }
}

extern "C" void kernel_launch(void* const* d_in, const int* in_sizes, int n_in,
                              void* d_out, int out_size, void* d_ws, size_t ws_size,
                              hipStream_t stream) {
    const float* feats = (const float*)d_in[0];
    const float* ipos  = (const float*)d_in[1];
    const float* opos  = (const float*)d_in[2];
    const float* vsp   = (const float*)d_in[3];
    const float* W     = (const float*)d_in[4];
    const float* bias  = (const float*)d_in[5];

    int N = in_sizes[0] / 64;
    int M = out_size / 64;

    // workspace: imap | omap | ikey | okey | Wt4   (no clearing required)
    int*    imap = (int*)d_ws;
    int*    omap = imap + NROWS;
    int*    ikey = omap + NROWS;
    int*    okey = ikey + N;
    __bf16* Wt4  = (__bf16*)(okey + M);

    int total = N + M + 27*64*64;
    prep_kernel<<<(total + 255) / 256, 256, 0, stream>>>(ipos, N, opos, M, vsp, W,
                                                         imap, ikey, omap, okey, Wt4);
    conv_kernel<<<8 * SLAB, 256, 0, stream>>>(feats, Wt4, bias, imap, ikey, omap, okey,
                                              (float*)d_out, N, M);
}

// Round 2
// 164.258 us; speedup vs baseline: 1.5448x; 1.5448x over previous
//
#include <hip/hip_runtime.h>
#include <math.h>

// ---- geometry ----
// Grid 50^3, coords shifted +1 -> occupy [1,50]. Dense key = (z*GY+y)*64+x.
// 8-deep z bricks probe z up to 57 -> z-dim 58.
#define GY 54
#define ZD 58
#define NROWS (ZD*GY*64)      // 200448 keys

// brick 8x4x8 = 256 output voxels per block; halo 10x6x10 = 600 rows
#define HX 10
#define HY 6
#define HXY 60                // halo rows per z-slice
#define NH 600
#define NBX 7
#define NBY 13
#define NBZ 7
#define NBRICK (NBX*NBY*NBZ)  // 637
#define SLAB 80               // ceil(637/8)

// B staged in two tap chunks so LDS fits 3 blocks/CU (51.3 KB total)
#define TAPS_C0 14
#define TAPS_C1 13

typedef __bf16  bf16x8 __attribute__((ext_vector_type(8)));
typedef float  f32x16 __attribute__((ext_vector_type(16)));

// ---- fused prep: maps + reverse keys + W -> Wt4 [4 ci-quarters][27][64cout][16cin] ----
__global__ void prep_kernel(const float* __restrict__ ipos, int n,
                            const float* __restrict__ opos, int m,
                            const float* __restrict__ vsp,
                            const float* __restrict__ W,
                            int* __restrict__ imap, int* __restrict__ ikey,
                            int* __restrict__ omap, int* __restrict__ okey,
                            __bf16* __restrict__ Wt4) {
    int i = blockIdx.x * 256 + threadIdx.x;
    float vs = vsp[0];
    if (i < n) {
        int x = (int)floorf(ipos[3*i+0] / vs) + 1;
        int y = (int)floorf(ipos[3*i+1] / vs) + 1;
        int z = (int)floorf(ipos[3*i+2] / vs) + 1;
        int key = (z * GY + y) * 64 + x;
        ikey[i] = key;
        imap[key] = i;
    } else if (i < n + m) {
        int j = i - n;
        int x = (int)floorf(opos[3*j+0] / vs) + 1;
        int y = (int)floorf(opos[3*j+1] / vs) + 1;
        int z = (int)floorf(opos[3*j+2] / vs) + 1;
        int key = (z * GY + y) * 64 + x;
        okey[j] = key;
        omap[key] = j;
    } else if (i < n + m + 27*64*64) {
        int k  = i - n - m;
        int t  = k >> 12;
        int r  = k & 4095;
        int ci = r >> 6;
        int co = r & 63;
        int p   = ci >> 4;
        int cil = ci & 15;
        Wt4[(((p * 27 + t) << 6) + co) * 16 + cil] = (__bf16)W[k];
    }
}

// inline tap body -- NO lambda (a by-reference lambda capture of the
// accumulators demoted them to scratch in a previous attempt: symmetric
// ~250MB FETCH/WRITE blowup = spill traffic). Macro keeps acc in VGPRs.
#define TAP_BODY(t, tc)                                                       \
    {                                                                         \
        const int dx = (t) % 3 - 1;                                           \
        const int dy = ((t) / 3) % 3 - 1;                                     \
        const int dz = (t) / 9 - 1;                                           \
        const int doff = (dz * HXY + dy * HX + dx) * 16;                      \
        bf16x8 a0 = *(const bf16x8*)(Ab0 + doff);                             \
        bf16x8 a1 = *(const bf16x8*)(Ab1 + doff);                             \
        bf16x8 b0 = *(const bf16x8*)(Bb0 + (tc) * 1024);                      \
        bf16x8 b1 = *(const bf16x8*)(Bb1 + (tc) * 1024);                      \
        acc00 = __builtin_amdgcn_mfma_f32_32x32x16_bf16(a0, b0, acc00, 0, 0, 0); \
        acc01 = __builtin_amdgcn_mfma_f32_32x32x16_bf16(a0, b1, acc01, 0, 0, 0); \
        acc10 = __builtin_amdgcn_mfma_f32_32x32x16_bf16(a1, b0, acc10, 0, 0, 0); \
        acc11 = __builtin_amdgcn_mfma_f32_32x32x16_bf16(a1, b1, acc11, 0, 0, 0); \
    }

__global__ __launch_bounds__(256, 2) void conv_kernel(
    const float* __restrict__ feats,    // [N,64] fp32
    const __bf16* __restrict__ Wt4,     // [4][27][64cout][16cin]
    const float* __restrict__ bias,     // [64]
    const int*   __restrict__ imap,
    const int*   __restrict__ ikey,
    const int*   __restrict__ omap,
    const int*   __restrict__ okey,
    float*       __restrict__ out,      // [M,64]
    int N, int M)
{
    __shared__ __align__(16) __bf16 halo[NH * 16];            // 19200 B (row = 16 cin, 32B)
    __shared__ __align__(16) __bf16 Bq[TAPS_C0 * 64 * 16];    // 28672 B (one tap chunk, quarter-K)
    __shared__ int ridx[NH];                                  //  2400 B
    __shared__ int obuf[256];                                 //  1024 B
    // total ~51.3 KB -> 3 blocks/CU (12 waves/CU); all 637 bricks co-resident

    const int tid = threadIdx.x;

    // XCD slab swizzle
    int q = (blockIdx.x & 7) * SLAB + (blockIdx.x >> 3);
    if (q >= NBRICK) return;   // block-uniform exit before any barrier
    const int bx = q % NBX;
    int rem = q / NBX;
    const int by = rem % NBY;
    const int bz = rem / NBY;

    // ---- resolve halo row indices (validated) + output rows ----
    #pragma unroll
    for (int it = 0; it < 3; ++it) {
        int r = it * 256 + tid;
        if (r < NH) {
            int xs = r % HX;
            int t2 = r / HX;
            int ys = t2 % HY;
            int zs = t2 / HY;
            int key = ((bz*8 + zs) * GY + (by*4 + ys)) * 64 + (bx*8 + xs);
            int idx = imap[key];
            int c = min(max(idx, 0), N - 1);
            ridx[r] = (idx >= 0 && idx < N && ikey[c] == key) ? idx : -1;
        }
    }
    {
        int x = tid & 7, y = (tid >> 3) & 3, z = tid >> 5;
        int key = ((bz*8 + z + 1) * GY + (by*4 + y + 1)) * 64 + (bx*8 + x + 1);
        int o = omap[key];
        int c = min(max(o, 0), M - 1);
        obuf[tid] = (o >= 0 && o < M && okey[c] == key) ? o : -1;
    }

    // compute roles: wave owns z-slices {2w, 2w+1} (2 m-tiles) x both n-tiles
    const int wave  = tid >> 6;
    const int lane  = tid & 63;
    const int lrow  = lane & 31;
    const int halfk = lane >> 5;
    const int xv = lrow & 7, yv = (lrow >> 3) & 3;
    // A row index (halo row units) for m-tile 0 of this wave, before tap offset
    const int arow0 = (2*wave + 1) * HXY + (yv + 1) * HX + (xv + 1);
    const __bf16* Ab0 = halo + arow0 * 16 + halfk * 8;      // m-tile 0
    const __bf16* Ab1 = Ab0 + HXY * 16;                     // m-tile 1 (z+1)
    const __bf16* Bb0 = Bq + lrow * 16 + halfk * 8;         // n-tile 0 (tap adds tc*1024)
    const __bf16* Bb1 = Bb0 + 32 * 16;                      // n-tile 1

    f32x16 acc00, acc01, acc10, acc11;
    #pragma unroll
    for (int i = 0; i < 16; ++i) { acc00[i]=0.f; acc01[i]=0.f; acc10[i]=0.f; acc11[i]=0.f; }

    __syncthreads();   // ridx + obuf visible

    #pragma unroll 1
    for (int p = 0; p < 4; ++p) {
        if (p) __syncthreads();   // previous pass's readers done before overwrite

        // ---- fill halo quarter: 600 rows x 16 cin (fp32 -> bf16) ----
        #pragma unroll
        for (int it = 0; it < 5; ++it) {
            int task = it * 256 + tid;
            if (task < NH * 2) {
                int r = task >> 1, hf = task & 1;   // hf: 8-channel half of the quarter
                int idx = ridx[r];
                bf16x8 v;
                if (idx >= 0) {
                    const float4* s = (const float4*)(feats + (size_t)idx * 64 + p * 16 + hf * 8);
                    float4 f0 = s[0], f1 = s[1];
                    v[0]=(__bf16)f0.x; v[1]=(__bf16)f0.y; v[2]=(__bf16)f0.z; v[3]=(__bf16)f0.w;
                    v[4]=(__bf16)f1.x; v[5]=(__bf16)f1.y; v[6]=(__bf16)f1.z; v[7]=(__bf16)f1.w;
                } else {
                    #pragma unroll
                    for (int j = 0; j < 8; ++j) v[j] = (__bf16)0.f;
                }
                *(bf16x8*)(halo + r * 16 + hf * 8) = v;
            }
        }

        // ---- fill B chunk 0: taps 0..13 (coalesced bf16 copy) ----
        {
            const __bf16* Wp = Wt4 + (size_t)p * 27648;
            #pragma unroll
            for (int it = 0; it < 7; ++it) {
                int task = it * 256 + tid;           // 1792 chunks exactly
                *(bf16x8*)(Bq + task * 8) = *(const bf16x8*)(Wp + task * 8);
            }
        }

        __syncthreads();   // halo + Bq chunk 0 visible

        #pragma unroll
        for (int t = 0; t < TAPS_C0; ++t) TAP_BODY(t, t)

        __syncthreads();   // chunk-0 readers done before Bq overwrite

        // ---- fill B chunk 1: taps 14..26 ----
        {
            const __bf16* Wp = Wt4 + (size_t)p * 27648 + TAPS_C0 * 1024;
            #pragma unroll
            for (int it = 0; it < 7; ++it) {
                int task = it * 256 + tid;           // 1664 chunks
                if (task < TAPS_C1 * 128)
                    *(bf16x8*)(Bq + task * 8) = *(const bf16x8*)(Wp + task * 8);
            }
        }

        __syncthreads();   // Bq chunk 1 visible (halo untouched)

        #pragma unroll
        for (int t = TAPS_C0; t < 27; ++t) TAP_BODY(t, t - TAPS_C0)
    }

    // ---- epilogue: C/D layout col=lane&31, row=(reg&3)+8*(reg>>2)+4*(lane>>5) ----
    const int col0 = lrow, col1 = 32 + lrow;
    const float bv0 = bias[col0], bv1 = bias[col1];
    #pragma unroll
    for (int r = 0; r < 16; ++r) {
        int mrow = (r & 3) + 8 * (r >> 2) + 4 * halfk;
        int o0 = obuf[(2*wave)     * 32 + mrow];
        int o1 = obuf[(2*wave + 1) * 32 + mrow];
        if (o0 >= 0) {
            out[(size_t)o0 * 64 + col0] = acc00[r] + bv0;
            out[(size_t)o0 * 64 + col1] = acc01[r] + bv1;
        }
        if (o1 >= 0) {
            out[(size_t)o1 * 64 + col0] = acc10[r] + bv0;
            out[(size_t)o1 * 64 + col1] = acc11[r] + bv1;
        }
    }
}

extern "C" void kernel_launch(void* const* d_in, const int* in_sizes, int n_in,
                              void* d_out, int out_size, void* d_ws, size_t ws_size,
                              hipStream_t stream) {
    const float* feats = (const float*)d_in[0];
    const float* ipos  = (const float*)d_in[1];
    const float* opos  = (const float*)d_in[2];
    const float* vsp   = (const float*)d_in[3];
    const float* W     = (const float*)d_in[4];
    const float* bias  = (const float*)d_in[5];

    int N = in_sizes[0] / 64;
    int M = out_size / 64;

    // workspace: imap | omap | ikey | okey | Wt4   (no clearing required)
    int*    imap = (int*)d_ws;
    int*    omap = imap + NROWS;
    int*    ikey = omap + NROWS;
    int*    okey = ikey + N;
    __bf16* Wt4  = (__bf16*)(okey + M);

    int total = N + M + 27*64*64;
    prep_kernel<<<(total + 255) / 256, 256, 0, stream>>>(ipos, N, opos, M, vsp, W,
                                                         imap, ikey, omap, okey, Wt4);
    conv_kernel<<<8 * SLAB, 256, 0, stream>>>(feats, Wt4, bias, imap, ikey, omap, okey,
                                              (float*)d_out, N, M);
}